// Round 10
// baseline (170.883 us; speedup 1.0000x reference)
//
#include <hip/hip_runtime.h>

// MultiLIF forward: B=32, L=2048, K=512. Fused producer/consumer kernel, R10.
// 512 blocks x 640 threads, 32 chains/block => 2 blocks/CU (20 waves/CU).
// Rationale: R7-R9 invariance at ~80us = memory service rate 8 B/cyc/CU
// (5.0 TB/s chip mixed) with ONE barrier-locked block/CU issuing in bursts;
// fillBuffer hits 7 TB/s with many continuously-issuing waves. 2 blocks/CU
// doubles issuing waves and interleaves windows (block B issues while block A
// waits), smoothing demand.
// Per block:
//   wave 0   : serial LIF scan from LDS ring (lanes 0..31 own chains; lanes
//              32..63 duplicate harmlessly); setprio(1).
//   wave 1   : DMA issuer, 8x global_load_lds width-16 (1KB = 8 time-rows)
//              per window into a 5-chunk (40KB) ring; s_waitcnt vmcnt(24)
//              (chunks w+2..w+4 in flight), never 0; tail issues clamped
//              garbage to keep the count uniform.
//   waves 2-9: expanders, 8 time-rows x {spikes,series} each per window,
//              dwordx4 nt stores, stateless from packed bits; never wait on
//              vmcnt.
// Barriers per window (raw s_barrier, never __syncthreads/vmcnt(0)):
//   B_A: chunk w resident.  B_B: ring slot (w%5) free; packed[w&1] visible.
//
// Numerics (absmax 0, proven R5-R9): x/20, x/100 via split-constant fma
// (single rounding of x*(HI+LO), err ~2^-49 vs >=~2^-30 midpoint margin ->
// == IEEE division for all f32). th = 1 + 1.5*a separate mul+add (contract
// off). Spike select/reset exact; counts small ints, exact in f32.

#define LL 2048
#define KK 512

typedef float f4v __attribute__((ext_vector_type(4)));
typedef unsigned u4v __attribute__((ext_vector_type(4)));

constexpr int CHN = 32;         // chains per block
constexpr int CH = 64;          // steps per chunk/window
constexpr int NWIN = LL / CH;   // 32
constexpr int NCH = 5;          // ring chunks: 40 KB, 3-window read slack

constexpr float C20_HI = 0.05f;
constexpr float C20_LO = (float)(0.05 - (double)C20_HI);
constexpr float C100_HI = 0.01f;
constexpr float C100_LO = (float)(0.01 - (double)C100_HI);

__global__ __launch_bounds__(640, 1) void lif_fused(const float* __restrict__ I,
                                                    float* __restrict__ spikes,
                                                    float* __restrict__ series) {
#pragma clang fp contract(off)
    __shared__ float ring[NCH][CH][CHN];  // 40 KB
    __shared__ unsigned pbl[2][CHN];      // packed spike bits t=0..31
    __shared__ unsigned pbh[2][CHN];      // packed spike bits t=32..63
    __shared__ float pbase[2][CHN];       // chunk-base running count

    const int tid = threadIdx.x;
    const int wid = tid >> 6;
    const int l = tid & 63;
    const int e0 = blockIdx.x * CHN;      // first chain of this block
    const int b = e0 >> 9;
    const int k0 = e0 & 511;
    const size_t base = (size_t)b * LL * KK;

    if (wid == 1) {
        // ---------------- DMA issuer ----------------
        // lane l sources row (l>>3) of an 8-row group, cols 4*(l&7)..+3;
        // LDS landing = dest + l*16B == [8][32] row-major: exact match.
        const float* g0 = I + base + (size_t)(l >> 3) * KK + (k0 + 4 * (l & 7));

        for (int c = 0; c < NCH - 1; ++c) {
#pragma unroll
            for (int j = 0; j < 8; ++j) {
                const float* g = g0 + (size_t)(c * CH + 8 * j) * KK;
                __builtin_amdgcn_global_load_lds(
                    (const __attribute__((address_space(1))) void*)g,
                    (__attribute__((address_space(3))) void*)&ring[c][8 * j][0],
                    16, 0, 0);
            }
        }
        for (int w = 0; w <= NWIN; ++w) {
            int c = w + NCH - 1;
            if (c > NWIN - 1) c = NWIN - 1;         // tail: clamped garbage
            const int slot = (w + NCH - 1) % NCH;   // freed at B_B(w-1)
#pragma unroll
            for (int j = 0; j < 8; ++j) {
                const float* g = g0 + (size_t)(c * CH + 8 * j) * KK;
                __builtin_amdgcn_global_load_lds(
                    (const __attribute__((address_space(1))) void*)g,
                    (__attribute__((address_space(3))) void*)&ring[slot][8 * j][0],
                    16, 0, 0);
            }
            // 40 outstanding after issue; keep 3 chunks (24): w,w+1 landed
            asm volatile("s_waitcnt vmcnt(24)" ::: "memory");
            asm volatile("s_barrier" ::: "memory");    // B_A
            asm volatile("s_barrier" ::: "memory");    // B_B
        }
    } else if (wid == 0) {
        // ---------------- consumer: serial scan ----------------
        __builtin_amdgcn_s_setprio(1);
        const int lc = l & 31;                     // lanes 32..63 duplicate
        float v = 0.0f, a = 0.0f, n = 0.0f;
        for (int w = 0; w <= NWIN; ++w) {
            asm volatile("s_barrier" ::: "memory");    // B_A: chunk w resident
            if (w < NWIN) {
                const int slot = w % NCH;
                unsigned bl = 0, bh = 0;
                float cur[4], nxt[4];
#pragma unroll
                for (int i = 0; i < 4; ++i) cur[i] = ring[slot][i][lc];
                if (l < CHN) pbase[w & 1][lc] = n;     // count BEFORE chunk
#pragma unroll
                for (int q = 0; q < 16; ++q) {
                    if (q < 15) {
#pragma unroll
                        for (int i = 0; i < 4; ++i)
                            nxt[i] = ring[slot][4 * q + 4 + i][lc];
                    }
#pragma unroll
                    for (int i = 0; i < 4; ++i) {
                        const float It = cur[i];
                        const float d1 = __builtin_fmaf(v, C20_HI, v * C20_LO);
                        v = v - d1 + It;               // (v - v/20) + I_t
                        const float th = 1.0f + 1.5f * a;
                        const bool fired = (v >= th);
                        const float s1 = fired ? 1.0f : 0.0f;
                        n = n + s1;
                        v = fired ? -0.5f : v;         // exact reset select
                        const float d2 = __builtin_fmaf(a, C100_HI, a * C100_LO);
                        a = a - d2 + s1;               // (a - a/100) + s
                        const unsigned bit = fired ? 1u : 0u;
                        const int t = 4 * q + i;       // compile-time
                        if (t < 32) bl |= bit << t;
                        else        bh |= bit << (t - 32);
                    }
#pragma unroll
                    for (int i = 0; i < 4; ++i) cur[i] = nxt[i];
                }
                if (l < CHN) {
                    pbl[w & 1][lc] = bl;
                    pbh[w & 1][lc] = bh;
                }
            }
            asm volatile("s_waitcnt lgkmcnt(0)" ::: "memory");
            asm volatile("s_barrier" ::: "memory");    // B_B
        }
    } else {
        // -------- expanders (wid 2..9): 8 time-rows x 2 arrays each --------
        const int xi = wid - 2;                    // 0..7: rows 8*xi..8*xi+7
        const int kq = 4 * (l & 7);                // chain quad this lane
        const int tr = l >> 3;                     // row within 8-row group
        const int t = 8 * xi + tr;                 // absolute step in window
        const bool sel = (xi >= 4);                // wave-uniform: t >= 32
        const int tt = t & 31;
        const unsigned mask = (2u << tt) - 1u;     // tt=31 -> all ones
        float* spb = spikes + base + (k0 + kq);
        float* ssb = series + base + (k0 + kq);
        for (int w = 0; w <= NWIN; ++w) {
            asm volatile("s_barrier" ::: "memory");    // B_A
            if (w >= 1) {
                const int c = w - 1;
                const int p = c & 1;
                const u4v lo = *(const u4v*)&pbl[p][kq];
                const u4v hi = *(const u4v*)&pbh[p][kq];
                const f4v pb = *(const f4v*)&pbase[p][kq];
                f4v vs, vn;
#pragma unroll
                for (int j = 0; j < 4; ++j) {
                    const unsigned w32 = sel ? hi[j] : lo[j];
                    const float pre = sel ? (float)__popc(lo[j]) : 0.0f;
                    vs[j] = (float)((w32 >> tt) & 1u);
                    vn[j] = pb[j] + (pre + (float)__popc(w32 & mask));
                }
                const size_t off = (size_t)(c * CH + t) * KK;
                __builtin_nontemporal_store(vs, (f4v*)(spb + off));
                __builtin_nontemporal_store(vn, (f4v*)(ssb + off));
            }
            asm volatile("s_barrier" ::: "memory");    // B_B
        }
    }
}

extern "C" void kernel_launch(void* const* d_in, const int* in_sizes, int n_in,
                              void* d_out, int out_size, void* d_ws, size_t ws_size,
                              hipStream_t stream) {
    const float* I = (const float*)d_in[0];
    float* spikes = (float*)d_out;
    float* series = (float*)d_out + (size_t)32 * LL * KK;
    lif_fused<<<512, 640, 0, stream>>>(I, spikes, series);
}

// Round 11
// 79.691 us; speedup vs baseline: 2.1443x; 2.1443x over previous
//
#include <hip/hip_runtime.h>

// MultiLIF forward: B=32, L=2048, K=512. Fused producer/consumer kernel.
// REVERT to R9 (best: 79.9us). R10's 2-blocks/CU failed its prerequisite:
// only one 640-thread block co-resided per CU (Occupancy 28.6% ~= 10 waves)
// -> two sequential half-width passes -> 171us. This structure: 256 blocks x
// 704 threads (11 waves/CU, 1 block/CU, 64 chains/block):
//   wave 0    : serial LIF scan from LDS ring only; setprio(1).
//   waves 1-2 : DMA issuers, global_load_lds width-16 (1KB/instr), 8 per
//               window each, into a 5-chunk (80KB) ring; counted
//               s_waitcnt vmcnt(24) (chunks w+2..w+4 in flight), never 0.
//   waves 3-10: expanders, 2 time-quads each (16 quads = 64 rows/window),
//               dwordx4 nt stores, values stateless from packed bits.
// Barriers per window (raw s_barrier, never __syncthreads/vmcnt(0)):
//   B_A: chunk w resident in LDS.  B_B: ring slot (w%5) free; packed[w&1]
//   visible to expanders at window w+1.
// Pipeline pacer (R7-R10 evidence): per-CU mixed memory service ~8 B/cyc
// (5.0 TB/s chip, vs 6.3 TB/s copy / 7 TB/s fill ceilings). Store width,
// barrier count, ring depth, and block count all benched null or worse.
//
// Numerics (absmax 0, proven R5-R10): x/20, x/100 via split-constant fma
// (single rounding of x*(HI+LO), err ~2^-49 vs >=~2^-30 midpoint margin ->
// == IEEE division for all f32). th = 1 + 1.5*a separate mul+add (contract
// off). Spike select/reset exact; counts small ints, exact in f32.

#define LL 2048
#define KK 512

typedef float f4v __attribute__((ext_vector_type(4)));
typedef unsigned u4v __attribute__((ext_vector_type(4)));

constexpr int CH = 64;          // steps per chunk/window
constexpr int NWIN = LL / CH;   // 32
constexpr int NCH = 5;          // ring chunks: 80 KB, 3-window read slack

constexpr float C20_HI = 0.05f;
constexpr float C20_LO = (float)(0.05 - (double)C20_HI);
constexpr float C100_HI = 0.01f;
constexpr float C100_LO = (float)(0.01 - (double)C100_HI);

__global__ __launch_bounds__(704, 1) void lif_fused(const float* __restrict__ I,
                                                    float* __restrict__ spikes,
                                                    float* __restrict__ series) {
#pragma clang fp contract(off)
    __shared__ float ring[NCH][CH][64];   // 80 KB
    __shared__ unsigned pbl[2][64];       // packed spike bits t=0..31
    __shared__ unsigned pbh[2][64];       // packed spike bits t=32..63
    __shared__ float pbase[2][64];        // chunk-base running count

    const int tid = threadIdx.x;
    const int wid = tid >> 6;
    const int l = tid & 63;
    const int e0 = blockIdx.x * 64;       // first chain of this block
    const int b = e0 >> 9;
    const int k0 = e0 & 511;
    const size_t base = (size_t)b * LL * KK;

    if (wid == 1 || wid == 2) {
        // ---------------- DMA issuers ----------------
        const int j0 = (wid - 1) * 8;     // time-quads j0..j0+7 of each chunk
        const float* g0 = I + base + (size_t)(l >> 4) * KK + (k0 + 4 * (l & 15));

        for (int c = 0; c < NCH - 1; ++c) {
#pragma unroll
            for (int jj = 0; jj < 8; ++jj) {
                const int j = j0 + jj;
                const float* g = g0 + (size_t)(c * CH + 4 * j) * KK;
                __builtin_amdgcn_global_load_lds(
                    (const __attribute__((address_space(1))) void*)g,
                    (__attribute__((address_space(3))) void*)&ring[c][4 * j][0],
                    16, 0, 0);
            }
        }
        for (int w = 0; w <= NWIN; ++w) {
            int c = w + NCH - 1;
            if (c > NWIN - 1) c = NWIN - 1;         // tail: clamped garbage
            const int slot = (w + NCH - 1) % NCH;   // freed at B_B(w-1)
#pragma unroll
            for (int jj = 0; jj < 8; ++jj) {
                const int j = j0 + jj;
                const float* g = g0 + (size_t)(c * CH + 4 * j) * KK;
                __builtin_amdgcn_global_load_lds(
                    (const __attribute__((address_space(1))) void*)g,
                    (__attribute__((address_space(3))) void*)&ring[slot][4 * j][0],
                    16, 0, 0);
            }
            // 5 chunks x8 outstanding after issue; keep 3 chunks (24):
            // chunks w and w+1 landed (margin 1)
            asm volatile("s_waitcnt vmcnt(24)" ::: "memory");
            asm volatile("s_barrier" ::: "memory");    // B_A
            asm volatile("s_barrier" ::: "memory");    // B_B
        }
    } else if (wid == 0) {
        // ---------------- consumer: serial scan ----------------
        __builtin_amdgcn_s_setprio(1);
        float v = 0.0f, a = 0.0f, n = 0.0f;
        for (int w = 0; w <= NWIN; ++w) {
            asm volatile("s_barrier" ::: "memory");    // B_A: chunk w resident
            if (w < NWIN) {
                const int slot = w % NCH;
                pbase[w & 1][l] = n;                   // count BEFORE chunk
                unsigned bl = 0, bh = 0;
                float cur[4], nxt[4];
#pragma unroll
                for (int i = 0; i < 4; ++i) cur[i] = ring[slot][i][l];
#pragma unroll
                for (int q = 0; q < 16; ++q) {
                    if (q < 15) {
#pragma unroll
                        for (int i = 0; i < 4; ++i)
                            nxt[i] = ring[slot][4 * q + 4 + i][l];
                    }
#pragma unroll
                    for (int i = 0; i < 4; ++i) {
                        const float It = cur[i];
                        const float d1 = __builtin_fmaf(v, C20_HI, v * C20_LO);
                        v = v - d1 + It;               // (v - v/20) + I_t
                        const float th = 1.0f + 1.5f * a;
                        const bool fired = (v >= th);
                        const float s1 = fired ? 1.0f : 0.0f;
                        n = n + s1;
                        v = fired ? -0.5f : v;         // exact reset select
                        const float d2 = __builtin_fmaf(a, C100_HI, a * C100_LO);
                        a = a - d2 + s1;               // (a - a/100) + s
                        const unsigned bit = fired ? 1u : 0u;
                        const int t = 4 * q + i;       // compile-time
                        if (t < 32) bl |= bit << t;
                        else        bh |= bit << (t - 32);
                    }
#pragma unroll
                    for (int i = 0; i < 4; ++i) cur[i] = nxt[i];
                }
                pbl[w & 1][l] = bl;
                pbh[w & 1][l] = bh;
            }
            asm volatile("s_waitcnt lgkmcnt(0)" ::: "memory");
            asm volatile("s_barrier" ::: "memory");    // B_B
        }
    } else {
        // ------------- expanders (wid 3..10): 2 time-quads each -------------
        const int xi = wid - 3;                        // 0..7
        const int kq = 4 * (l & 15);                   // chain quad this lane
        const int tr = l >> 4;                         // row within time-quad
        float* spb = spikes + base + (k0 + kq);
        float* ssb = series + base + (k0 + kq);
        for (int w = 0; w <= NWIN; ++w) {
            asm volatile("s_barrier" ::: "memory");    // B_A
            if (w >= 1) {
                const int c = w - 1;
                const int p = c & 1;
                const u4v lo = *(const u4v*)&pbl[p][kq];
                const u4v hi = *(const u4v*)&pbh[p][kq];
                const f4v pb = *(const f4v*)&pbase[p][kq];
#pragma unroll
                for (int qi = 0; qi < 2; ++qi) {
                    const int q = 2 * xi + qi;         // 0..15, wave-uniform
                    const int t = 4 * q + tr;
                    const bool sel = (q >= 8);
                    const int tt = t & 31;
                    const unsigned mask = (2u << tt) - 1u;  // tt=31 -> all ones
                    f4v vs, vn;
#pragma unroll
                    for (int j = 0; j < 4; ++j) {
                        const unsigned w32 = sel ? hi[j] : lo[j];
                        const float pre = sel ? (float)__popc(lo[j]) : 0.0f;
                        vs[j] = (float)((w32 >> tt) & 1u);
                        vn[j] = pb[j] + (pre + (float)__popc(w32 & mask));
                    }
                    const size_t off = (size_t)(c * CH + t) * KK;
                    __builtin_nontemporal_store(vs, (f4v*)(spb + off));
                    __builtin_nontemporal_store(vn, (f4v*)(ssb + off));
                }
            }
            asm volatile("s_barrier" ::: "memory");    // B_B
        }
    }
}

extern "C" void kernel_launch(void* const* d_in, const int* in_sizes, int n_in,
                              void* d_out, int out_size, void* d_ws, size_t ws_size,
                              hipStream_t stream) {
    const float* I = (const float*)d_in[0];
    float* spikes = (float*)d_out;
    float* series = (float*)d_out + (size_t)32 * LL * KK;
    lif_fused<<<256, 704, 0, stream>>>(I, spikes, series);
}